// Round 13
// baseline (2367.011 us; speedup 1.0000x reference)
//
#include <hip/hip_runtime.h>
#include <hip/hip_fp16.h>
#include <math.h>
#include <stdint.h>

typedef _Float16 f16;
typedef _Float16 h8 __attribute__((ext_vector_type(8)));
typedef float f4 __attribute__((ext_vector_type(4)));

#define TSTEPS 48

#define MFMA(a,b,c) __builtin_amdgcn_mfma_f32_16x16x32_f16((a),(b),(c),0,0,0)
// inline-asm MFMA with acc and B pinned to the AGPR half of the unified file
#define MFMA_AB(acc, a, b) \
  asm("v_mfma_f32_16x16x32_f16 %0, %1, %2, %0" : "+a"(acc) : "v"(a), "a"(b))

__device__ __forceinline__ float gelu_f(float x) {
  float ax = fabsf(x) * 0.7071067811865475f;
  float t = __builtin_amdgcn_rcpf(1.0f + 0.3275911f * ax);
  float poly = t * (0.254829592f + t * (-0.284496736f + t * (1.421413741f +
               t * (-1.453152027f + t * 1.061405429f))));
  float e = exp2f(-ax * ax * 1.4426950408889634f);
  float er = copysignf(1.0f - poly * e, x);
  return 0.5f * x * (1.0f + er);
}

__device__ __forceinline__ float tanh_f(float x) {
  float e = exp2f(x * 2.885390081777927f);
  return 1.0f - 2.0f * __builtin_amdgcn_rcpf(e + 1.0f);
}

// ---------------- unified lane-linear weight prep ----------------
// Fragment (kk, cf): 16 cols c0=cf*16, 32 k's at kk*32. Lane ln holds 8 f16:
// dst[fragid*512 + ln*8 + e] = src[(kk*32 + (ln>>4)*8 + e) * N + cf*16 + (ln&15)]
__global__ void prep_lin(const float* __restrict__ src, f16* __restrict__ dst,
                         int Kreal, int N, int total) {
  int idx = blockIdx.x * 256 + threadIdx.x;
  if (idx >= total) return;
  int fragid = idx >> 9;
  int within = idx & 511;
  int ln = within >> 3, e = within & 7;
  int nfr = N >> 4;
  int kk = fragid / nfr, cf = fragid - kk * nfr;
  int k = kk * 32 + ((ln >> 4) << 3) + e;
  int n = (cf << 4) + (ln & 15);
  dst[idx] = (f16)((k < Kreal) ? src[k * N + n] : 0.f);
}

// ---------------- feature kernel: fourier + hashgrid + z -> fp16 [B][192] ----
__global__ void feat_kernel(const float* __restrict__ x, const float* __restrict__ z,
                            const float* __restrict__ tables, const int* __restrict__ res,
                            const float* __restrict__ freqs, f16* __restrict__ featsH) {
  __shared__ f16 rowbuf[64][194];
  const int t = threadIdx.x;        // 64 threads
  const int b = blockIdx.x;
  const int i = b * 64 + t;

  float xv = x[i];
  float xn = fminf(fmaxf(xv, 0.f), 1.f);
  f16* dst = rowbuf[t];
  dst[0] = (f16)xn;
  float w2pi = 6.283185307179586f * xn;
  #pragma unroll
  for (int k = 0; k < 32; ++k) {
    float a = w2pi * freqs[k];
    float s, c;
    sincosf(a, &s, &c);
    dst[1 + k]  = (f16)s;
    dst[33 + k] = (f16)c;
  }
  #pragma unroll
  for (int l = 0; l < 8; ++l) {
    int R = res[l];
    int Rm1 = R - 1;
    float tt = xn * (float)Rm1;
    int i0 = (int)tt;
    int i1 = min(i0 + 1, Rm1);
    float w = tt - (float)i0;
    uint32_t lt = (uint32_t)(l * 19349663);
    uint32_t h0 = (((uint32_t)i0 * 73856093u) ^ lt) & 16383u;
    uint32_t h1 = (((uint32_t)i1 * 73856093u) ^ lt) & 16383u;
    const float* e0 = tables + ((size_t)l * 16384 + h0) * 8;
    const float* e1 = tables + ((size_t)l * 16384 + h1) * 8;
    #pragma unroll
    for (int e = 0; e < 8; ++e) {
      float v = e0[e] * (1.f - w) + e1[e] * w;
      dst[65 + l * 8 + e] = (f16)v;
    }
  }
  #pragma unroll
  for (int j = 0; j < 32; ++j) dst[129 + j] = (f16)z[(size_t)i * 32 + j];
  #pragma unroll
  for (int j = 161; j < 192; ++j) dst[j] = (f16)0.f;

  __syncthreads();
  uint32_t* dg = (uint32_t*)(featsH + (size_t)b * 64 * 192);
  for (int idx = t; idx < 64 * 96; idx += 64) {
    int row = idx / 96, o = idx - row * 96;
    dg[idx] = ((const uint32_t*)&rowbuf[row][0])[o];
  }
}

// ---------------- main fused kernel ----------------
// 256 blocks x 512 threads (8 waves), 1 block/CU, 2 waves/SIMD (256 regs/wave).
// KEY: the wave-stationary Wf2 slice (32 x h8 = 128 regs) is pinned in the
// ACC (AGPR) half of the unified register file via inline-asm MFMA with "a"
// constraints. R5-R9's spills happened because intrinsic-MFMA operands fought
// for the 128-reg ARCH half; accum_offset is flexible, so arch ~90 + acc 160
// (128 wB + 32 acc) fits. GEMM2 runs with ZERO weight loads -> streamed
// demand halves to Wf1-only (3.15 GB).
// Master h is f32 in LDS (mB; R11-verified numerics). Wf1 streamed lane-linear
// with ring-4 distance-3 register prefetch (R9-verified, 16%4==0).
// LDS 160KB: hB 32K (h f16, swz) + uB 64K (u f16; feats staging) + mB 64K (f32).
__global__ __launch_bounds__(512)
__attribute__((amdgpu_waves_per_eu(2, 2)))
void fractal_main(
    const f16* __restrict__ featsH,
    const f16* __restrict__ W1L, const f16* __restrict__ W2L,
    const f16* __restrict__ WoL,
    const f16* __restrict__ Wf1L, const f16* __restrict__ Wf2L,
    const float* __restrict__ b1, const float* __restrict__ b2,
    const float* __restrict__ bf1, const float* __restrict__ bf2,
    const float* __restrict__ bo,
    float* __restrict__ out) {
  extern __shared__ char smem[];
  char* hB = smem;             // 32KB
  char* uB = smem + 32768;     // 64KB
  char* mB = smem + 98304;     // 64KB (f32 master h)

  const int tid = threadIdx.x;
  const int wn  = tid >> 6;          // 0..7
  const int ln  = tid & 63;
  const int r   = ln & 15;
  const int g   = ln >> 4;
  const int sw  = (r & 7) << 4;
  const int g16 = g * 16;
  const int row0 = blockIdx.x * 64;

  const int cH = 32 * wn + r;        // wave's HID-col base (+16*nf)
  float b1r[2], b2r[2], bf2r[2], bor[2], bf1r[4];
  #pragma unroll
  for (int nf = 0; nf < 2; ++nf) {
    b1r[nf] = b1[cH + 16 * nf]; b2r[nf] = b2[cH + 16 * nf];
    bf2r[nf] = bf2[cH + 16 * nf]; bor[nf] = bo[cH + 16 * nf];
  }
  #pragma unroll
  for (int nf = 0; nf < 4; ++nf) bf1r[nf] = bf1[64 * wn + 16 * nf + r];

  // lane-linear stream bases
  const f16* w1b  = W1L  + (2 * wn) * 512 + ln * 8;   // frag kk*16 + 2wn + nf
  const f16* w2b  = W2L  + (2 * wn) * 512 + ln * 8;
  const f16* wob  = WoL  + (2 * wn) * 512 + ln * 8;
  const f16* wf1b = Wf1L + (4 * wn) * 512 + ln * 8;   // frag kk*32 + 4wn + 2q + nf
  const f16* wf2b = Wf2L + (2 * wn) * 512 + ln * 8;   // frag kk*16 + 2wn + nf

  // ---- stage feats tile into uB (swizzled, row stride 384B) ----
  {
    const char* src = (const char*)featsH + (size_t)row0 * 384;
    for (int i = tid; i < 6144; i += 512) {
      int row = i / 96;
      int off = (i - row * 96) * 4;
      uint32_t v = *(const uint32_t*)(src + (size_t)i * 4);
      *(uint32_t*)(uB + row * 384 + (off ^ ((row & 7) << 4))) = v;
    }
  }
  __syncthreads();

  const f4 zf = {0.f, 0.f, 0.f, 0.f};

  // ---- layer 1: h1 = gelu(feats @ W1 + b1) -> hB ----
  {
    f4 acc[4][2];
    #pragma unroll
    for (int mf = 0; mf < 4; ++mf)
      #pragma unroll
      for (int nf = 0; nf < 2; ++nf) acc[mf][nf] = zf;
    #pragma unroll
    for (int kk = 0; kk < 6; ++kk) {
      h8 bb[2];
      #pragma unroll
      for (int nf = 0; nf < 2; ++nf)
        bb[nf] = *(const h8*)(w1b + ((size_t)(kk * 16 + nf) << 9));
      #pragma unroll
      for (int mf = 0; mf < 4; ++mf) {
        h8 a = *(const h8*)(uB + (16 * mf + r) * 384 + ((kk * 64 + g16) ^ sw));
        #pragma unroll
        for (int nf = 0; nf < 2; ++nf)
          acc[mf][nf] = MFMA(a, bb[nf], acc[mf][nf]);
      }
    }
    __syncthreads();   // uB reads done
    #pragma unroll
    for (int mf = 0; mf < 4; ++mf)
      #pragma unroll
      for (int nf = 0; nf < 2; ++nf)
        #pragma unroll
        for (int j = 0; j < 4; ++j) {
          float hv = gelu_f(acc[mf][nf][j] + b1r[nf]);
          int row = 16 * mf + g * 4 + j;
          int col = cH + 16 * nf;
          *(f16*)(hB + row * 512 + ((col * 2) ^ ((row & 7) << 4))) = (f16)hv;
        }
  }
  __syncthreads();

  // ---- layer 2: h0 = gelu(h1 @ W2 + b2) -> hB + mB(f32) ----
  {
    f4 acc[4][2];
    #pragma unroll
    for (int mf = 0; mf < 4; ++mf)
      #pragma unroll
      for (int nf = 0; nf < 2; ++nf) acc[mf][nf] = zf;
    #pragma unroll
    for (int kk = 0; kk < 8; ++kk) {
      h8 bb[2];
      #pragma unroll
      for (int nf = 0; nf < 2; ++nf)
        bb[nf] = *(const h8*)(w2b + ((size_t)(kk * 16 + nf) << 9));
      #pragma unroll
      for (int mf = 0; mf < 4; ++mf) {
        h8 a = *(const h8*)(hB + (16 * mf + r) * 512 + ((kk * 64 + g16) ^ sw));
        #pragma unroll
        for (int nf = 0; nf < 2; ++nf)
          acc[mf][nf] = MFMA(a, bb[nf], acc[mf][nf]);
      }
    }
    __syncthreads();   // h1 reads done before overwrite
    #pragma unroll
    for (int mf = 0; mf < 4; ++mf)
      #pragma unroll
      for (int nf = 0; nf < 2; ++nf)
        #pragma unroll
        for (int j = 0; j < 4; ++j) {
          float hv = gelu_f(acc[mf][nf][j] + b2r[nf]);
          int row = 16 * mf + g * 4 + j;
          int col = cH + 16 * nf;
          *(f16*)(hB + row * 512 + ((col * 2) ^ ((row & 7) << 4))) = (f16)hv;
          *(float*)(mB + row * 1024 + ((col * 4) ^ ((row & 7) << 4))) = hv;
        }
  }
  __syncthreads();

  // ---- preload wave-stationary Wf2 slice; pin into the AGPR half ----
  h8 wB[16][2];
  #pragma unroll
  for (int kk = 0; kk < 16; ++kk)
    #pragma unroll
    for (int nf = 0; nf < 2; ++nf) {
      wB[kk][nf] = *(const h8*)(wf2b + ((size_t)(kk * 16 + nf) << 9));
      asm("" : "+a"(wB[kk][nf]));   // force ACC register class immediately
    }

  // ---- prime Wf1 ring (ring-4, distance-3; 16%4==0 phase-consistent) ----
  h8 pf[4][2];
  #pragma unroll
  for (int p = 0; p < 3; ++p)
    #pragma unroll
    for (int nf = 0; nf < 2; ++nf)
      pf[p][nf] = *(const h8*)(wf1b +
        ((size_t)((p & 7) * 32 + 2 * (p >> 3) + nf) << 9));

  // ---- 48 fractal steps ----
  #pragma unroll 1
  for (int t = 0; t < TSTEPS; ++t) {
    // GEMM1: u = gelu(h @ Wf1 + bf1), wave cols [64wn,+64) in two 32-col halves
    #pragma unroll
    for (int q = 0; q < 2; ++q) {
      f4 a1[4][2];
      #pragma unroll
      for (int mf = 0; mf < 4; ++mf)
        #pragma unroll
        for (int nf = 0; nf < 2; ++nf) a1[mf][nf] = zf;
      #pragma unroll
      for (int kk = 0; kk < 8; ++kk) {
        const int i = q * 8 + kk;
        const int ip = (i + 3) & 15;           // wraps to next t (t-invariant)
        #pragma unroll
        for (int nf = 0; nf < 2; ++nf)
          pf[(i + 3) & 3][nf] = *(const h8*)(wf1b +
            ((size_t)((ip & 7) * 32 + 2 * (ip >> 3) + nf) << 9));
        #pragma unroll
        for (int mf = 0; mf < 4; ++mf) {
          h8 a = *(const h8*)(hB + (16 * mf + r) * 512 + ((kk * 64 + g16) ^ sw));
          #pragma unroll
          for (int nf = 0; nf < 2; ++nf)
            a1[mf][nf] = MFMA(a, pf[i & 3][nf], a1[mf][nf]);
        }
      }
      #pragma unroll
      for (int mf = 0; mf < 4; ++mf)
        #pragma unroll
        for (int nf = 0; nf < 2; ++nf)
          #pragma unroll
          for (int j = 0; j < 4; ++j) {
            float gv = gelu_f(a1[mf][nf][j] + bf1r[q * 2 + nf]);
            int row = 16 * mf + g * 4 + j;
            int col = 64 * wn + 32 * q + 16 * nf + r;
            *(f16*)(uB + row * 1024 + ((col * 2) ^ ((row & 7) << 4))) = (f16)gv;
          }
    }
    __syncthreads();

    // GEMM2: h' = 0.5*(m + tanh(u @ Wf2 + bf2)) — B pinned in AGPRs, zero loads
    f4 a2[4][2];
    #pragma unroll
    for (int mf = 0; mf < 4; ++mf)
      #pragma unroll
      for (int nf = 0; nf < 2; ++nf) a2[mf][nf] = zf;
    #pragma unroll
    for (int kk = 0; kk < 16; ++kk) {
      #pragma unroll
      for (int mf = 0; mf < 4; ++mf) {
        h8 a = *(const h8*)(uB + (16 * mf + r) * 1024 + ((kk * 64 + g16) ^ sw));
        MFMA_AB(a2[mf][0], a, wB[kk][0]);
        MFMA_AB(a2[mf][1], a, wB[kk][1]);
      }
    }
    #pragma unroll
    for (int mf = 0; mf < 4; ++mf)
      #pragma unroll
      for (int nf = 0; nf < 2; ++nf)
        #pragma unroll
        for (int j = 0; j < 4; ++j) {
          int row = 16 * mf + g * 4 + j;
          int col = cH + 16 * nf;
          float* mp = (float*)(mB + row * 1024 + ((col * 4) ^ ((row & 7) << 4)));
          float u = tanh_f(a2[mf][nf][j] + bf2r[nf]);
          float hn = 0.5f * (*mp + u);
          *mp = hn;
          *(f16*)(hB + row * 512 + ((col * 2) ^ ((row & 7) << 4))) = (f16)hn;
        }
    __syncthreads();
  }

  // ---- final: out = h @ Wo + bo ----
  {
    f4 acc[4][2];
    #pragma unroll
    for (int mf = 0; mf < 4; ++mf)
      #pragma unroll
      for (int nf = 0; nf < 2; ++nf) acc[mf][nf] = zf;
    #pragma unroll
    for (int kk = 0; kk < 8; ++kk) {
      h8 bb[2];
      #pragma unroll
      for (int nf = 0; nf < 2; ++nf)
        bb[nf] = *(const h8*)(wob + ((size_t)(kk * 16 + nf) << 9));
      #pragma unroll
      for (int mf = 0; mf < 4; ++mf) {
        h8 a = *(const h8*)(hB + (16 * mf + r) * 512 + ((kk * 64 + g16) ^ sw));
        #pragma unroll
        for (int nf = 0; nf < 2; ++nf)
          acc[mf][nf] = MFMA(a, bb[nf], acc[mf][nf]);
      }
    }
    #pragma unroll
    for (int mf = 0; mf < 4; ++mf)
      #pragma unroll
      for (int nf = 0; nf < 2; ++nf)
        #pragma unroll
        for (int j = 0; j < 4; ++j) {
          int row = row0 + 16 * mf + g * 4 + j;
          int col = cH + 16 * nf;
          out[(size_t)row * 256 + col] = acc[mf][nf][j] + bor[nf];
        }
  }
}

// ---------------- host launch ----------------
extern "C" void kernel_launch(void* const* d_in, const int* in_sizes, int n_in,
                              void* d_out, int out_size, void* d_ws, size_t ws_size,
                              hipStream_t stream) {
  const float* x      = (const float*)d_in[0];
  const float* z      = (const float*)d_in[1];
  const float* tables = (const float*)d_in[2];
  const float* W1     = (const float*)d_in[3];
  const float* b1     = (const float*)d_in[4];
  const float* W2     = (const float*)d_in[5];
  const float* b2     = (const float*)d_in[6];
  const float* Wf1    = (const float*)d_in[7];
  const float* bf1    = (const float*)d_in[8];
  const float* Wf2    = (const float*)d_in[9];
  const float* bf2    = (const float*)d_in[10];
  const float* Wo     = (const float*)d_in[11];
  const float* bo     = (const float*)d_in[12];
  const int*   res    = (const int*)d_in[13];
  const float* freqs  = (const float*)d_in[14];
  float* out = (float*)d_out;

  char* ws = (char*)d_ws;
  f16* featsH = (f16*)(ws);                 // 16384*192*2 = 6291456
  f16* W1L    = (f16*)(ws + 6291456);       // 96 frags  * 1KB = 98304
  f16* W2L    = (f16*)(ws + 6389760);       // 128 frags * 1KB = 131072
  f16* WoL    = (f16*)(ws + 6520832);       // 131072
  f16* Wf1L   = (f16*)(ws + 6651904);       // 256 frags * 1KB = 262144
  f16* Wf2L   = (f16*)(ws + 6914048);       // 262144

  prep_lin<<<192, 256, 0, stream>>>(W1,  W1L,  161, 256, 96  * 512);
  prep_lin<<<256, 256, 0, stream>>>(W2,  W2L,  256, 256, 128 * 512);
  prep_lin<<<256, 256, 0, stream>>>(Wo,  WoL,  256, 256, 128 * 512);
  prep_lin<<<512, 256, 0, stream>>>(Wf1, Wf1L, 256, 512, 256 * 512);
  prep_lin<<<512, 256, 0, stream>>>(Wf2, Wf2L, 512, 256, 256 * 512);
  feat_kernel<<<256, 64, 0, stream>>>(x, z, tables, res, freqs, featsH);

  (void)hipFuncSetAttribute((const void*)fractal_main,
                            hipFuncAttributeMaxDynamicSharedMemorySize, 163840);
  fractal_main<<<256, 512, 163840, stream>>>(featsH, W1L, W2L, WoL, Wf1L, Wf2L,
                                             b1, b2, bf1, bf2, bo, out);
}

// Round 14
// 970.241 us; speedup vs baseline: 2.4396x; 2.4396x over previous
//
#include <hip/hip_runtime.h>
#include <hip/hip_fp16.h>
#include <math.h>
#include <stdint.h>

typedef _Float16 f16;
typedef _Float16 h8 __attribute__((ext_vector_type(8)));
typedef float f4 __attribute__((ext_vector_type(4)));

#define TSTEPS 48

#define MFMA(a,b,c) __builtin_amdgcn_mfma_f32_16x16x32_f16((a),(b),(c),0,0,0)
// inline-asm MFMA with acc and B pinned to the AGPR half of the unified file
#define MFMA_AB(acc, a, b) \
  asm("v_mfma_f32_16x16x32_f16 %0, %1, %2, %0" : "+a"(acc) : "v"(a), "a"(b))

__device__ __forceinline__ float gelu_f(float x) {
  float ax = fabsf(x) * 0.7071067811865475f;
  float t = __builtin_amdgcn_rcpf(1.0f + 0.3275911f * ax);
  float poly = t * (0.254829592f + t * (-0.284496736f + t * (1.421413741f +
               t * (-1.453152027f + t * 1.061405429f))));
  float e = exp2f(-ax * ax * 1.4426950408889634f);
  float er = copysignf(1.0f - poly * e, x);
  return 0.5f * x * (1.0f + er);
}

__device__ __forceinline__ float tanh_f(float x) {
  float e = exp2f(x * 2.885390081777927f);
  return 1.0f - 2.0f * __builtin_amdgcn_rcpf(e + 1.0f);
}

__device__ __forceinline__ void gload_lds16(const void* g, void* l) {
  __builtin_amdgcn_global_load_lds(
      (const __attribute__((address_space(1))) void*)g,
      (__attribute__((address_space(3))) void*)l, 16, 0, 0);
}

// ---------------- unified lane-linear weight prep (W1/W2/Wo/Wf2) ----------------
// Fragment (kk, cf): 16 cols c0=cf*16, 32 k's at kk*32. Lane ln holds 8 f16:
// dst[fragid*512 + ln*8 + e] = src[(kk*32 + (ln>>4)*8 + e) * N + cf*16 + (ln&15)]
__global__ void prep_lin(const float* __restrict__ src, f16* __restrict__ dst,
                         int Kreal, int N, int total) {
  int idx = blockIdx.x * 256 + threadIdx.x;
  if (idx >= total) return;
  int fragid = idx >> 9;
  int within = idx & 511;
  int ln = within >> 3, e = within & 7;
  int nfr = N >> 4;
  int kk = fragid / nfr, cf = fragid - kk * nfr;
  int k = kk * 32 + ((ln >> 4) << 3) + e;
  int n = (cf << 4) + (ln & 15);
  dst[idx] = (f16)((k < Kreal) ? src[k * N + n] : 0.f);
}

// ---------------- Wf1 chunk stream: 16 chunks of 16KB ----------------
// chunk c = (h*8 + kk): k-slice [32kk,+32) x cols [256h,+256) as 16 lane-linear
// 1KB frags (frag cf: cols [256h+16cf,+16)).
__global__ void prep_wf1c(const float* __restrict__ src, f16* __restrict__ dst) {
  int idx = blockIdx.x * 256 + threadIdx.x;    // 131072
  if (idx >= 131072) return;
  int f = idx >> 9, w = idx & 511;
  int ln = w >> 3, e = w & 7;
  int cf = f & 15, kk = (f >> 4) & 7, h = f >> 7;
  int n = 256 * h + 16 * cf + (ln & 15);
  int k = 32 * kk + 8 * (ln >> 4) + e;
  dst[idx] = (f16)src[k * 512 + n];            // Wf1 [256][512]
}

// ---------------- feature kernel: fourier + hashgrid + z -> fp16 [B][192] ----
__global__ void feat_kernel(const float* __restrict__ x, const float* __restrict__ z,
                            const float* __restrict__ tables, const int* __restrict__ res,
                            const float* __restrict__ freqs, f16* __restrict__ featsH) {
  __shared__ f16 rowbuf[64][194];
  const int t = threadIdx.x;        // 64 threads
  const int b = blockIdx.x;
  const int i = b * 64 + t;

  float xv = x[i];
  float xn = fminf(fmaxf(xv, 0.f), 1.f);
  f16* dst = rowbuf[t];
  dst[0] = (f16)xn;
  float w2pi = 6.283185307179586f * xn;
  #pragma unroll
  for (int k = 0; k < 32; ++k) {
    float a = w2pi * freqs[k];
    float s, c;
    sincosf(a, &s, &c);
    dst[1 + k]  = (f16)s;
    dst[33 + k] = (f16)c;
  }
  #pragma unroll
  for (int l = 0; l < 8; ++l) {
    int R = res[l];
    int Rm1 = R - 1;
    float tt = xn * (float)Rm1;
    int i0 = (int)tt;
    int i1 = min(i0 + 1, Rm1);
    float w = tt - (float)i0;
    uint32_t lt = (uint32_t)(l * 19349663);
    uint32_t h0 = (((uint32_t)i0 * 73856093u) ^ lt) & 16383u;
    uint32_t h1 = (((uint32_t)i1 * 73856093u) ^ lt) & 16383u;
    const float* e0 = tables + ((size_t)l * 16384 + h0) * 8;
    const float* e1 = tables + ((size_t)l * 16384 + h1) * 8;
    #pragma unroll
    for (int e = 0; e < 8; ++e) {
      float v = e0[e] * (1.f - w) + e1[e] * w;
      dst[65 + l * 8 + e] = (f16)v;
    }
  }
  #pragma unroll
  for (int j = 0; j < 32; ++j) dst[129 + j] = (f16)z[(size_t)i * 32 + j];
  #pragma unroll
  for (int j = 161; j < 192; ++j) dst[j] = (f16)0.f;

  __syncthreads();
  uint32_t* dg = (uint32_t*)(featsH + (size_t)b * 64 * 192);
  for (int idx = t; idx < 64 * 96; idx += 64) {
    int row = idx / 96, o = idx - row * 96;
    dg[idx] = ((const uint32_t*)&rowbuf[row][0])[o];
  }
}

// ---------------- main fused kernel ----------------
// 256 blocks x 512 threads (8 waves), 1 block/CU, 2 waves/SIMD (256 regs).
// Wf2: wave-stationary slice in AGPRs (R13-verified). Wf1: fire-and-forget
// global_load_lds chunk pipeline, counted vmcnt(4) (never 0 in loop), 3
// rotating 16KB slots, depth 2. Each wave stages/consumes ONLY its own 2KB of
// each chunk -> zero cross-wave hazards on wbuf; no extra barriers.
// Master h = f16 hi (hB) + f16 lo (loB) (R12-verified numerics).
// LDS 144K: hB 32K + uB 32K (half-tile u) + loB 32K + wbuf 48K.
__global__ __launch_bounds__(512)
__attribute__((amdgpu_waves_per_eu(2, 2)))
void fractal_main(
    const f16* __restrict__ featsH,
    const f16* __restrict__ W1L, const f16* __restrict__ W2L,
    const f16* __restrict__ WoL,
    const f16* __restrict__ Wf1C, const f16* __restrict__ Wf2L,
    const float* __restrict__ b1, const float* __restrict__ b2,
    const float* __restrict__ bf1, const float* __restrict__ bf2,
    const float* __restrict__ bo,
    float* __restrict__ out) {
  extern __shared__ char smem[];
  char* hB   = smem;             // 32KB: h hi [64][256] f16 swz
  char* uB   = smem + 32768;     // 32KB: u half [64][256] f16 swz (feats staging)
  char* loB  = smem + 65536;     // 32KB: h lo
  char* wbuf = smem + 98304;     // 48KB: 3 x 16KB Wf1 chunk slots

  const int tid = threadIdx.x;
  const int wn  = tid >> 6;          // 0..7
  const int ln  = tid & 63;
  const int r   = ln & 15;
  const int g   = ln >> 4;
  const int sw  = (r & 7) << 4;
  const int g16 = g * 16;
  const int row0 = blockIdx.x * 64;

  const int cH = 32 * wn + r;        // wave's col base in N=256 ops (+16*nf)
  float b1r[2], b2r[2], bf2r[2], bor[2];
  #pragma unroll
  for (int nf = 0; nf < 2; ++nf) {
    b1r[nf] = b1[cH + 16 * nf]; b2r[nf] = b2[cH + 16 * nf];
    bf2r[nf] = bf2[cH + 16 * nf]; bor[nf] = bo[cH + 16 * nf];
  }
  float bf1r[2][2];                  // [h][nf]: GEMM1 col = 256h + 32wn+16nf+r
  #pragma unroll
  for (int h = 0; h < 2; ++h)
    #pragma unroll
    for (int nf = 0; nf < 2; ++nf)
      bf1r[h][nf] = bf1[256 * h + cH + 16 * nf];

  const f16* w1b  = W1L  + (2 * wn) * 512 + ln * 8;
  const f16* w2b  = W2L  + (2 * wn) * 512 + ln * 8;
  const f16* wob  = WoL  + (2 * wn) * 512 + ln * 8;
  const f16* wf2b = Wf2L + (2 * wn) * 512 + ln * 8;

  // ---- stage feats tile into uB (swizzled, row stride 384B) ----
  {
    const char* src = (const char*)featsH + (size_t)row0 * 384;
    for (int i = tid; i < 6144; i += 512) {
      int row = i / 96;
      int off = (i - row * 96) * 4;
      uint32_t v = *(const uint32_t*)(src + (size_t)i * 4);
      *(uint32_t*)(uB + row * 384 + (off ^ ((row & 7) << 4))) = v;
    }
  }
  __syncthreads();

  const f4 zf = {0.f, 0.f, 0.f, 0.f};

  // ---- layer 1: h1 = gelu(feats @ W1 + b1) -> hB ----
  {
    f4 acc[4][2];
    #pragma unroll
    for (int mf = 0; mf < 4; ++mf)
      #pragma unroll
      for (int nf = 0; nf < 2; ++nf) acc[mf][nf] = zf;
    #pragma unroll
    for (int kk = 0; kk < 6; ++kk) {
      h8 bb[2];
      #pragma unroll
      for (int nf = 0; nf < 2; ++nf)
        bb[nf] = *(const h8*)(w1b + ((size_t)(kk * 16 + nf) << 9));
      #pragma unroll
      for (int mf = 0; mf < 4; ++mf) {
        h8 a = *(const h8*)(uB + (16 * mf + r) * 384 + ((kk * 64 + g16) ^ sw));
        #pragma unroll
        for (int nf = 0; nf < 2; ++nf)
          acc[mf][nf] = MFMA(a, bb[nf], acc[mf][nf]);
      }
    }
    __syncthreads();   // uB (feats) reads done
    #pragma unroll
    for (int mf = 0; mf < 4; ++mf)
      #pragma unroll
      for (int nf = 0; nf < 2; ++nf)
        #pragma unroll
        for (int j = 0; j < 4; ++j) {
          float hv = gelu_f(acc[mf][nf][j] + b1r[nf]);
          int row = 16 * mf + g * 4 + j;
          int col = cH + 16 * nf;
          *(f16*)(hB + row * 512 + ((col * 2) ^ ((row & 7) << 4))) = (f16)hv;
        }
  }
  __syncthreads();

  // ---- layer 2: h0 = gelu(h1 @ W2 + b2) -> hB(hi) + loB(lo) ----
  {
    f4 acc[4][2];
    #pragma unroll
    for (int mf = 0; mf < 4; ++mf)
      #pragma unroll
      for (int nf = 0; nf < 2; ++nf) acc[mf][nf] = zf;
    #pragma unroll
    for (int kk = 0; kk < 8; ++kk) {
      h8 bb[2];
      #pragma unroll
      for (int nf = 0; nf < 2; ++nf)
        bb[nf] = *(const h8*)(w2b + ((size_t)(kk * 16 + nf) << 9));
      #pragma unroll
      for (int mf = 0; mf < 4; ++mf) {
        h8 a = *(const h8*)(hB + (16 * mf + r) * 512 + ((kk * 64 + g16) ^ sw));
        #pragma unroll
        for (int nf = 0; nf < 2; ++nf)
          acc[mf][nf] = MFMA(a, bb[nf], acc[mf][nf]);
      }
    }
    __syncthreads();   // h1 reads done before overwrite
    #pragma unroll
    for (int mf = 0; mf < 4; ++mf)
      #pragma unroll
      for (int nf = 0; nf < 2; ++nf)
        #pragma unroll
        for (int j = 0; j < 4; ++j) {
          float hv = gelu_f(acc[mf][nf][j] + b2r[nf]);
          int row = 16 * mf + g * 4 + j;
          int col = cH + 16 * nf;
          int so = (col * 2) ^ ((row & 7) << 4);
          f16 hi = (f16)hv;
          *(f16*)(hB + row * 512 + so) = hi;
          *(f16*)(loB + row * 512 + so) = (f16)(hv - (float)hi);
        }
  }
  __syncthreads();

  // ---- Wf2 wave slice -> AGPRs (R13-verified mechanism) ----
  h8 wB[16][2];
  #pragma unroll
  for (int kk = 0; kk < 16; ++kk)
    #pragma unroll
    for (int nf = 0; nf < 2; ++nf) {
      wB[kk][nf] = *(const h8*)(wf2b + ((size_t)(kk * 16 + nf) << 9));
      asm("" : "+a"(wB[kk][nf]));
    }

  // ---- Wf1 chunk pipeline: prologue (issue chunks 0,1) ----
  // chunk c: Wf1C + c*8192 f16 (16KB); wave's 2KB at +wn*2048, lane +ln*16.
  const char* wsrc = (const char*)Wf1C + wn * 2048 + ln * 16;
  char* wdst = wbuf + wn * 2048;
  #pragma unroll
  for (int c = 0; c < 2; ++c) {
    gload_lds16(wsrc + c * 16384, wdst + c * 16384);
    gload_lds16(wsrc + c * 16384 + 1024, wdst + c * 16384 + 1024);
  }
  int iad = 2, isl = 2, csl = 0;     // issue addr-chunk, issue slot, consume slot

  // ---- 48 fractal steps ----
  #pragma unroll 1
  for (int t = 0; t < TSTEPS; ++t) {
    f4 a2[4][2];
    #pragma unroll
    for (int mf = 0; mf < 4; ++mf)
      #pragma unroll
      for (int nf = 0; nf < 2; ++nf) a2[mf][nf] = zf;

    #pragma unroll
    for (int h = 0; h < 2; ++h) {
      // GEMM1 half h: u_h = gelu(hB @ Wf1[:,256h:+256] + bf1)
      f4 a1[4][2];
      #pragma unroll
      for (int mf = 0; mf < 4; ++mf)
        #pragma unroll
        for (int nf = 0; nf < 2; ++nf) a1[mf][nf] = zf;
      #pragma unroll 1
      for (int kk = 0; kk < 8; ++kk) {
        // issue chunk jc+2 (depth 2, never drain in loop)
        gload_lds16(wsrc + iad * 16384, wdst + isl * 16384);
        gload_lds16(wsrc + iad * 16384 + 1024, wdst + isl * 16384 + 1024);
        iad = (iad + 1) & 15;
        isl = (isl == 2) ? 0 : isl + 1;
        asm volatile("s_waitcnt vmcnt(4)" ::: "memory");
        __builtin_amdgcn_sched_barrier(0);
        const char* wb = wbuf + csl * 16384 + (2 * wn) * 1024 + ln * 16;
        csl = (csl == 2) ? 0 : csl + 1;
        h8 bb0 = *(const h8*)(wb);
        h8 bb1 = *(const h8*)(wb + 1024);
        #pragma unroll
        for (int mf = 0; mf < 4; ++mf) {
          h8 a = *(const h8*)(hB + (16 * mf + r) * 512 + ((kk * 64 + g16) ^ sw));
          a1[mf][0] = MFMA(a, bb0, a1[mf][0]);
          a1[mf][1] = MFMA(a, bb1, a1[mf][1]);
        }
      }
      // epilogue half: gelu -> uB ([64][256], stride 512B, swz)
      #pragma unroll
      for (int mf = 0; mf < 4; ++mf)
        #pragma unroll
        for (int nf = 0; nf < 2; ++nf)
          #pragma unroll
          for (int j = 0; j < 4; ++j) {
            float gv = gelu_f(a1[mf][nf][j] + bf1r[h][nf]);
            int row = 16 * mf + g * 4 + j;
            int col = cH + 16 * nf;          // col within half
            *(f16*)(uB + row * 512 + ((col * 2) ^ ((row & 7) << 4))) = (f16)gv;
          }
      __syncthreads();

      // GEMM2 partial: a2 += u_h @ Wf2[256h:+256,:]  (B in AGPRs, zero loads)
      #pragma unroll
      for (int kk2 = 0; kk2 < 8; ++kk2) {
        #pragma unroll
        for (int mf = 0; mf < 4; ++mf) {
          h8 a = *(const h8*)(uB + (16 * mf + r) * 512 + ((kk2 * 64 + g16) ^ sw));
          MFMA_AB(a2[mf][0], a, wB[8 * h + kk2][0]);
          MFMA_AB(a2[mf][1], a, wB[8 * h + kk2][1]);
        }
      }
      __syncthreads();   // uB reads done before next half overwrites
    }

    // step epilogue: m = hi+lo; h' = 0.5*(m + tanh(a2+bf2)); write hi/lo
    #pragma unroll
    for (int mf = 0; mf < 4; ++mf)
      #pragma unroll
      for (int nf = 0; nf < 2; ++nf)
        #pragma unroll
        for (int j = 0; j < 4; ++j) {
          int row = 16 * mf + g * 4 + j;
          int col = cH + 16 * nf;
          int so = (col * 2) ^ ((row & 7) << 4);
          f16* hp = (f16*)(hB + row * 512 + so);
          f16* lp = (f16*)(loB + row * 512 + so);
          float mval = (float)*hp + (float)*lp;
          float u = tanh_f(a2[mf][nf][j] + bf2r[nf]);
          float hn = 0.5f * (mval + u);
          f16 hi = (f16)hn;
          *hp = hi;
          *lp = (f16)(hn - (float)hi);
        }
    __syncthreads();
  }

  // ---- final: out = h @ Wo + bo ----
  {
    f4 acc[4][2];
    #pragma unroll
    for (int mf = 0; mf < 4; ++mf)
      #pragma unroll
      for (int nf = 0; nf < 2; ++nf) acc[mf][nf] = zf;
    #pragma unroll
    for (int kk = 0; kk < 8; ++kk) {
      h8 bb[2];
      #pragma unroll
      for (int nf = 0; nf < 2; ++nf)
        bb[nf] = *(const h8*)(wob + ((size_t)(kk * 16 + nf) << 9));
      #pragma unroll
      for (int mf = 0; mf < 4; ++mf) {
        h8 a = *(const h8*)(hB + (16 * mf + r) * 512 + ((kk * 64 + g16) ^ sw));
        #pragma unroll
        for (int nf = 0; nf < 2; ++nf)
          acc[mf][nf] = MFMA(a, bb[nf], acc[mf][nf]);
      }
    }
    #pragma unroll
    for (int mf = 0; mf < 4; ++mf)
      #pragma unroll
      for (int nf = 0; nf < 2; ++nf)
        #pragma unroll
        for (int j = 0; j < 4; ++j) {
          int row = row0 + 16 * mf + g * 4 + j;
          int col = cH + 16 * nf;
          out[(size_t)row * 256 + col] = acc[mf][nf][j] + bor[nf];
        }
  }
}

// ---------------- host launch ----------------
extern "C" void kernel_launch(void* const* d_in, const int* in_sizes, int n_in,
                              void* d_out, int out_size, void* d_ws, size_t ws_size,
                              hipStream_t stream) {
  const float* x      = (const float*)d_in[0];
  const float* z      = (const float*)d_in[1];
  const float* tables = (const float*)d_in[2];
  const float* W1     = (const float*)d_in[3];
  const float* b1     = (const float*)d_in[4];
  const float* W2     = (const float*)d_in[5];
  const float* b2     = (const float*)d_in[6];
  const float* Wf1    = (const float*)d_in[7];
  const float* bf1    = (const float*)d_in[8];
  const float* Wf2    = (const float*)d_in[9];
  const float* bf2    = (const float*)d_in[10];
  const float* Wo     = (const float*)d_in[11];
  const float* bo     = (const float*)d_in[12];
  const int*   res    = (const int*)d_in[13];
  const float* freqs  = (const float*)d_in[14];
  float* out = (float*)d_out;

  char* ws = (char*)d_ws;
  f16* featsH = (f16*)(ws);                 // 16384*192*2 = 6291456
  f16* W1L    = (f16*)(ws + 6291456);       // 98304
  f16* W2L    = (f16*)(ws + 6389760);       // 131072
  f16* WoL    = (f16*)(ws + 6520832);       // 131072
  f16* Wf1C   = (f16*)(ws + 6651904);       // 262144 (16 x 16KB chunks)
  f16* Wf2L   = (f16*)(ws + 6914048);       // 262144 (lane-linear frags)

  prep_lin<<<192, 256, 0, stream>>>(W1,  W1L,  161, 256, 96  * 512);
  prep_lin<<<256, 256, 0, stream>>>(W2,  W2L,  256, 256, 128 * 512);
  prep_lin<<<256, 256, 0, stream>>>(Wo,  WoL,  256, 256, 128 * 512);
  prep_wf1c<<<512, 256, 0, stream>>>(Wf1, Wf1C);
  prep_lin<<<512, 256, 0, stream>>>(Wf2, Wf2L, 512, 256, 256 * 512);
  feat_kernel<<<256, 64, 0, stream>>>(x, z, tables, res, freqs, featsH);

  (void)hipFuncSetAttribute((const void*)fractal_main,
                            hipFuncAttributeMaxDynamicSharedMemorySize, 147456);
  fractal_main<<<256, 512, 147456, stream>>>(featsH, W1L, W2L, WoL, Wf1C, Wf2L,
                                             b1, b2, bf1, bf2, bo, out);
}